// Round 5
// baseline (41.607 us; speedup 1.0000x reference)
//
#include <hip/hip_runtime.h>

// ---------------- ws float offsets ----------------
enum : int {
  WS_H1 = 0,      // 64x128  composed node->f1 weight
  WS_H2 = 8192,   // 2x128   composed pos->f1 weight
  WS_H3 = 8448,   // 32x128  per-batch bias into f1 layer
  WS_END = 12544
};

// ---------------- K1: k_prep (64 blocks x 256) ----------------
// blocks 0..31: H1/H2 columns (4 per block, one 64-lane wave per column)
// blocks 32..63: per-batch H3 chain (batch = blk-32)
__global__ __launch_bounds__(256) void k_prep(
    const float* __restrict__ h, const float* __restrict__ pos,
    const float* __restrict__ se_w, const float* __restrict__ se_b,
    const float* __restrict__ s1_w, const float* __restrict__ s1_b,
    const float* __restrict__ s2_w, const float* __restrict__ s2_b,
    const float* __restrict__ n1_w, const float* __restrict__ n1_b,
    const float* __restrict__ n2_w, const float* __restrict__ n2_b,
    const float* __restrict__ e1_w, const float* __restrict__ e1_b,
    const float* __restrict__ e2_w, const float* __restrict__ e2_b,
    const float* __restrict__ f1_w, const float* __restrict__ f1_b,
    float* __restrict__ ws)
{
  int blk = blockIdx.x, t = threadIdx.x;
  if (blk < 32) {
    // ---- H1/H2 column chain ----
    __shared__ float wv[4][128];   // 128-vec stage (w1/w2/w3 reused)
    __shared__ float uv[4][64];    // 64-vec stage (u1/u2 reused)
    int g = t >> 6, lane = t & 63, c = blk * 4 + g;
    // P1: w1 = e2_w @ f1_w[:,c]
    { float a0 = 0.f, a1 = 0.f;
      #pragma unroll
      for (int k = 0; k < 64; ++k) {
        float f = f1_w[k * 128 + c];
        a0 = fmaf(e2_w[lane * 64 + k], f, a0);
        a1 = fmaf(e2_w[(lane + 64) * 64 + k], f, a1);
      }
      wv[g][lane] = a0; wv[g][lane + 64] = a1; }
    __syncthreads();
    // P2: u1 = E1r @ w1   (E1r = e1_w rows 0..63)
    { float a = 0.f;
      #pragma unroll
      for (int m = 0; m < 128; ++m) a = fmaf(e1_w[lane * 128 + m], wv[g][m], a);
      uv[g][lane] = a; }
    __syncthreads();
    // P3: w2 = n2_w @ u1
    { float b0 = 0.f, b1 = 0.f;
      #pragma unroll
      for (int k = 0; k < 64; ++k) {
        float u = uv[g][k];
        b0 = fmaf(n2_w[lane * 64 + k], u, b0);
        b1 = fmaf(n2_w[(lane + 64) * 64 + k], u, b1);
      }
      wv[g][lane] = b0; wv[g][lane + 64] = b1; }
    __syncthreads();
    // P4: u2 = n1_w @ w2
    { float a = 0.f;
      #pragma unroll
      for (int m = 0; m < 128; ++m) a = fmaf(n1_w[lane * 128 + m], wv[g][m], a);
      uv[g][lane] = a; }
    __syncthreads();
    // P5: w3 = s2_w @ u2
    { float b0 = 0.f, b1 = 0.f;
      #pragma unroll
      for (int k = 0; k < 64; ++k) {
        float u = uv[g][k];
        b0 = fmaf(s2_w[lane * 64 + k], u, b0);
        b1 = fmaf(s2_w[(lane + 64) * 64 + k], u, b1);
      }
      wv[g][lane] = b0; wv[g][lane + 64] = b1; }
    __syncthreads();
    // P6: H1[:,c] = 4*S1r@w3 ; z = S1e@w3 ; H2[:,c] = -4*se_w@z (wave reduce)
    { float a = 0.f, z = 0.f;
      #pragma unroll
      for (int m = 0; m < 128; ++m) {
        float w = wv[g][m];
        a = fmaf(s1_w[lane * 128 + m], w, a);
        z = fmaf(s1_w[(128 + lane) * 128 + m], w, z);
      }
      ws[WS_H1 + lane * 128 + c] = 4.f * a;
      float r0 = se_w[lane] * z, r1 = se_w[64 + lane] * z;
      #pragma unroll
      for (int m = 1; m < 64; m <<= 1) {
        r0 += __shfl_xor(r0, m, 64);
        r1 += __shfl_xor(r1, m, 64);
      }
      if (lane == 0) { ws[WS_H2 + c] = -4.f * r0; ws[WS_H2 + 128 + c] = -4.f * r1; } }
  } else {
    // ---- per-batch H3 chain ----
    int b = blk - 32;
    __shared__ float part[256], sX[64], sP[2];
    __shared__ float L0[128], L1[128], L2[128], L3[128], M0[64], M1[64];
    { int k = t & 63, g = t >> 6; float s = 0.f;
      #pragma unroll 8
      for (int j = g * 32; j < g * 32 + 32; ++j) s += h[(b * 128 + j) * 64 + k];
      part[t] = s; }
    __syncthreads();
    if (t < 64) sX[t] = (part[t] + part[64 + t]) + (part[128 + t] + part[192 + t]);
    else if (t < 66) { int cc = t - 64; float s = 0.f;
      #pragma unroll 16
      for (int j = 0; j < 128; ++j) s += pos[(b * 128 + j) * 2 + cc];
      sP[cc] = s; }
    __syncthreads();
    // Phase A: L0=xr=X@S1r, L1=k0=se_b@S1e+s1_b, L2=xs=X@S1s, L3=y=(P@se_w)@S1e
    { int g = t >> 7, o = t & 127;
      if (g == 0) {
        float a = 0.f, kk = 0.f;
        #pragma unroll
        for (int k = 0; k < 64; ++k) {
          a  = fmaf(sX[k],   s1_w[k * 128 + o],        a);
          kk = fmaf(se_b[k], s1_w[(128 + k) * 128 + o], kk);
        }
        L0[o] = a; L1[o] = kk + s1_b[o];
      } else {
        float p0 = sP[0], p1 = sP[1];
        float a = 0.f, yy = 0.f;
        #pragma unroll
        for (int k = 0; k < 64; ++k) {
          a = fmaf(sX[k], s1_w[(64 + k) * 128 + o], a);
          float qk = fmaf(p1, se_w[64 + k], p0 * se_w[k]);
          yy = fmaf(qk, s1_w[(128 + k) * 128 + o], yy);
        }
        L2[o] = a; L3[o] = yy;
      } }
    __syncthreads();
    // Phase B: M0 = v = ((xs+y)/64 + 2k0)@s2_w + 2*s2_b ; M1 = u = 2(xr-y)@s2_w
    if (t < 128) { int g = t >> 6, c = t & 63;
      float a = 0.f;
      if (g == 0) {
        #pragma unroll
        for (int o = 0; o < 128; ++o) {
          float r2 = fmaf(2.f, L1[o], (L2[o] + L3[o]) * (1.f / 64.f));
          a = fmaf(r2, s2_w[o * 64 + c], a);
        }
        M0[c] = a + 2.f * s2_b[c];
      } else {
        #pragma unroll
        for (int o = 0; o < 128; ++o)
          a = fmaf(2.f * (L0[o] - L3[o]), s2_w[o * 64 + c], a);
        M1[c] = a;
      } }
    __syncthreads();
    // Phase C: L0 = v@n1_w + n1_b ; L1 = u@n1_w
    { int g = t >> 7, o = t & 127;
      float a = 0.f;
      if (g == 0) {
        #pragma unroll
        for (int k = 0; k < 64; ++k) a = fmaf(M0[k], n1_w[k * 128 + o], a);
        L0[o] = a + n1_b[o];
      } else {
        #pragma unroll
        for (int k = 0; k < 64; ++k) a = fmaf(M1[k], n1_w[k * 128 + o], a);
        L1[o] = a;
      } }
    __syncthreads();
    // Phase D: M0 = c3 = m1@n2_w + n2_b ; M1 = un = m2@n2_w
    if (t < 128) { int g = t >> 6, c = t & 63;
      float a = 0.f;
      if (g == 0) {
        #pragma unroll
        for (int o = 0; o < 128; ++o) a = fmaf(L0[o], n2_w[o * 64 + c], a);
        M0[c] = a + n2_b[c];
      } else {
        #pragma unroll
        for (int o = 0; o < 128; ++o) a = fmaf(L1[o], n2_w[o * 64 + c], a);
        M1[c] = a;
      } }
    __syncthreads();
    // Phase E: L0 = ce = c3@E1r ; L1 = ne = (un + 128*c3)@E1s
    { int g = t >> 7, o = t & 127;
      float a = 0.f;
      if (g == 0) {
        #pragma unroll
        for (int k = 0; k < 64; ++k) a = fmaf(M0[k], e1_w[k * 128 + o], a);
        L0[o] = a;
      } else {
        #pragma unroll
        for (int k = 0; k < 64; ++k) {
          float nb = fmaf(128.f, M0[k], M1[k]);
          a = fmaf(nb, e1_w[(64 + k) * 128 + o], a);
        }
        L1[o] = a;
      } }
    __syncthreads();
    // Phase F: M0 = g3 = (2*ce + ne/64 + 2*e1_b)@e2_w + 2*e2_b
    if (t < 64) { float a = 0.f;
      #pragma unroll
      for (int o = 0; o < 128; ++o) {
        float gv = fmaf(L1[o], (1.f / 64.f), fmaf(2.f, L0[o], 2.f * e1_b[o]));
        a = fmaf(gv, e2_w[o * 64 + t], a);
      }
      M0[t] = a + 2.f * e2_b[t]; }
    __syncthreads();
    // Phase G: h3 = g3@f1_w + f1_b
    if (t < 128) { float a = 0.f;
      #pragma unroll
      for (int k = 0; k < 64; ++k) a = fmaf(M0[k], f1_w[k * 128 + t], a);
      ws[WS_H3 + b * 128 + t] = a + f1_b[t]; }
  }
}

// ---------------- K2: per-node fused MLP (LDS ~46 KB) ----------------
__global__ __launch_bounds__(256) void k_main(
    const float* __restrict__ h, const float* __restrict__ pos,
    const float* __restrict__ f2_w, const float* __restrict__ f2_b,
    const float* __restrict__ ws, float* __restrict__ out)
{
  __shared__ __align__(16) float lH1[64 * 128];  // [k][d]  32 KB
  __shared__ __align__(16) float lH2[2 * 128];
  __shared__ float lh3[128], lf2b[64];
  __shared__ __align__(16) float lx[16 * 64];    // [n][k]
  __shared__ float lp[16 * 2];
  __shared__ __align__(16) float lh1[16 * 128];  // [n][k]
  int blk = blockIdx.x, t = threadIdx.x;
  int b = blk >> 3, j0 = (blk & 7) * 16;
  for (int i = t; i < 2048; i += 256) ((float4*)lH1)[i] = ((const float4*)(ws + WS_H1))[i];
  for (int i = t; i < 64; i += 256) ((float4*)lH2)[i] = ((const float4*)(ws + WS_H2))[i];
  if (t < 128) lh3[t] = ws[WS_H3 + b * 128 + t];
  if (t < 64) lf2b[t] = f2_b[t];
  { ((float4*)lx)[t] = ((const float4*)(h + (size_t)(b * 128 + j0) * 64))[t]; }
  if (t < 32) lp[t] = pos[(b * 128 + j0) * 2 + t];
  __syncthreads();
  // h1 = relu(x@H1 + p@H2 + h3)
  {
    int d = t & 127, g = t >> 7, n0 = g * 8;
    float acc[8];
    #pragma unroll
    for (int i = 0; i < 8; ++i)
      acc[i] = lh3[d] + lp[(n0 + i) * 2] * lH2[d] + lp[(n0 + i) * 2 + 1] * lH2[128 + d];
    #pragma unroll 4
    for (int k = 0; k < 64; k += 4) {
      float h0 = lH1[k * 128 + d], h1v = lH1[(k + 1) * 128 + d],
            h2v = lH1[(k + 2) * 128 + d], h3v = lH1[(k + 3) * 128 + d];
      #pragma unroll
      for (int i = 0; i < 8; ++i) {
        float4 xv = *(const float4*)&lx[(n0 + i) * 64 + k];
        acc[i] = fmaf(xv.x, h0, fmaf(xv.y, h1v, fmaf(xv.z, h2v, fmaf(xv.w, h3v, acc[i]))));
      }
    }
    #pragma unroll
    for (int i = 0; i < 8; ++i) lh1[(n0 + i) * 128 + d] = fmaxf(acc[i], 0.f);
  }
  __syncthreads();
  // out = relu(h1@f2_w + f2_b); f2_w read from global (32 KB, L2-resident)
  {
    int d = t & 63, g = t >> 6, n0 = g * 4;
    float acc[4];
    #pragma unroll
    for (int i = 0; i < 4; ++i) acc[i] = lf2b[d];
    #pragma unroll 4
    for (int k = 0; k < 128; k += 4) {
      float f0 = f2_w[k * 64 + d], f1v = f2_w[(k + 1) * 64 + d],
            f2v = f2_w[(k + 2) * 64 + d], f3v = f2_w[(k + 3) * 64 + d];
      #pragma unroll
      for (int i = 0; i < 4; ++i) {
        float4 hv = *(const float4*)&lh1[(n0 + i) * 128 + k];
        acc[i] = fmaf(hv.x, f0, fmaf(hv.y, f1v, fmaf(hv.z, f2v, fmaf(hv.w, f3v, acc[i]))));
      }
    }
    #pragma unroll
    for (int i = 0; i < 4; ++i)
      out[(size_t)(b * 128 + j0 + n0 + i) * 64 + d] = fmaxf(acc[i], 0.f);
  }
}

extern "C" void kernel_launch(void* const* d_in, const int* in_sizes, int n_in,
                              void* d_out, int out_size, void* d_ws, size_t ws_size,
                              hipStream_t stream) {
  const float* h    = (const float*)d_in[0];
  const float* pos  = (const float*)d_in[1];
  const float* se_w = (const float*)d_in[2];
  const float* se_b = (const float*)d_in[3];
  const float* s1_w = (const float*)d_in[4];
  const float* s1_b = (const float*)d_in[5];
  const float* s2_w = (const float*)d_in[6];
  const float* s2_b = (const float*)d_in[7];
  const float* n1_w = (const float*)d_in[8];
  const float* n1_b = (const float*)d_in[9];
  const float* n2_w = (const float*)d_in[10];
  const float* n2_b = (const float*)d_in[11];
  const float* e1_w = (const float*)d_in[12];
  const float* e1_b = (const float*)d_in[13];
  const float* e2_w = (const float*)d_in[14];
  const float* e2_b = (const float*)d_in[15];
  const float* f1_w = (const float*)d_in[16];
  const float* f1_b = (const float*)d_in[17];
  const float* f2_w = (const float*)d_in[18];
  const float* f2_b = (const float*)d_in[19];
  float* ws = (float*)d_ws;
  float* out = (float*)d_out;

  hipLaunchKernelGGL(k_prep, dim3(64), dim3(256), 0, stream,
                     h, pos, se_w, se_b, s1_w, s1_b, s2_w, s2_b,
                     n1_w, n1_b, n2_w, n2_b, e1_w, e1_b, e2_w, e2_b,
                     f1_w, f1_b, ws);
  hipLaunchKernelGGL(k_main, dim3(256), dim3(256), 0, stream, h, pos, f2_w, f2_b, ws, out);
}